// Round 9
// baseline (406.208 us; speedup 1.0000x reference)
//
#include <hip/hip_runtime.h>
#include <hip/hip_bf16.h>
#include <stdint.h>

#define B_  32
#define L_  256
#define T_  32
#define D_  300
#define H_  256
#define G3  768   // 3*H

__device__ __forceinline__ int sdot4(uint32_t a, uint32_t b, int acc) {
#if defined(__has_builtin) && __has_builtin(__builtin_amdgcn_sdot4)
  return __builtin_amdgcn_sdot4((int)a, (int)b, acc, false);
#else
  const int a0 = (int)(signed char)(a & 0xff),  b0 = (int)(signed char)(b & 0xff);
  const int a1 = (int)(signed char)((a >> 8) & 0xff),  b1 = (int)(signed char)((b >> 8) & 0xff);
  const int a2 = (int)(signed char)((a >> 16) & 0xff), b2 = (int)(signed char)((b >> 16) & 0xff);
  const int a3 = (int)(signed char)(a >> 24),          b3 = (int)(signed char)(b >> 24);
  return acc + a0 * b0 + a1 * b1 + a2 * b2 + a3 * b3;
#endif
}

__device__ __forceinline__ float rcp_f(float x) { return __builtin_amdgcn_rcpf(x); }
__device__ __forceinline__ float sigmoid_f(float x) { return rcp_f(1.0f + __expf(-x)); }
__device__ __forceinline__ float tanh_f(float x) {
  float e2 = __expf(2.0f * x);
  return 1.0f - 2.0f * rcp_f(e2 + 1.0f);
}

// ---- pack Whh [768][256] f32 -> wQ i8 [64 kgroups][768 rows] + sw[768] ----
__global__ __launch_bounds__(256)
void pack_whh_i8(const float* __restrict__ Whh, uint32_t* __restrict__ wQ,
                 float* __restrict__ sw) {
  const int row = blockIdx.x * 4 + (threadIdx.x >> 6);
  const int lane = threadIdx.x & 63;
  const float* wr = Whh + (long)row * H_;
  float m = 0.0f;
#pragma unroll
  for (int u = 0; u < 4; ++u) m = fmaxf(m, fabsf(wr[lane + 64 * u]));
  for (int off = 32; off > 0; off >>= 1) m = fmaxf(m, __shfl_xor(m, off, 64));
  const float inv = m > 0.0f ? 127.0f / m : 0.0f;
  if (lane == 0) sw[row] = m > 0.0f ? m / (127.0f * 127.0f) : 0.0f;
  uint32_t d = 0;
#pragma unroll
  for (int u = 0; u < 4; ++u) {
    int qv = __float2int_rn(wr[4 * lane + u] * inv);
    qv = qv > 127 ? 127 : (qv < -127 ? -127 : qv);
    d |= ((uint32_t)(qv & 0xff)) << (8 * u);
  }
  wQ[lane * G3 + row] = d;
}

// ---- bsum = bih + bhh for gates r,z; bih only for gate n ----
__global__ void bias_combine(const float* __restrict__ bih, const float* __restrict__ bhh,
                             float* __restrict__ bsum) {
  const int i = blockIdx.x * 256 + threadIdx.x;   // 0..767
  float v = bih[i];
  if (i < 2 * H_) v += bhh[i];
  bsum[i] = v;
}

// ---- dtok[i] = Xin[b*L + Xindex[i]] ----
__global__ void gather_dtok(const int* __restrict__ Xin, const int* __restrict__ Xindex,
                            int* __restrict__ dtok) {
  const int i = blockIdx.x * 256 + threadIdx.x;   // 0..1023
  const int b = i >> 5;                           // /T_
  dtok[i] = Xin[b * L_ + Xindex[i]];
}

// ---- generic C = A @ W^T (+bias) ----
template<bool GATHER, bool TRANSP, bool BIAS>
__global__ __launch_bounds__(256)
void gemm_awt(const float* __restrict__ A, const int* __restrict__ rowidx,
              const float* __restrict__ W, const float* __restrict__ bias,
              float* __restrict__ C, int M, int N, int K) {
  __shared__ float As[16][68];
  __shared__ float Ws[16][68];
  const int tid = threadIdx.x;
  const int bm = blockIdx.x, bn = blockIdx.y;
  const int ty = tid >> 4, tx = tid & 15;
  const int r  = tid >> 2;
  const int c4 = (tid & 3) << 2;
  const long arow = (long)bm * 64 + r;
  const float* Arow = GATHER ? (A + (long)rowidx[arow] * K) : (A + arow * (long)K);
  const float* Wrow = W + ((long)bn * 64 + r) * K;
  float acc[4][4] = {};
  for (int k0 = 0; k0 < K; k0 += 16) {
    float4 av, wv;
    if (k0 + c4 + 3 < K) {
      av = *(const float4*)(Arow + k0 + c4);
      wv = *(const float4*)(Wrow + k0 + c4);
    } else {
      float ta[4] = {0, 0, 0, 0}, tw[4] = {0, 0, 0, 0};
      for (int u = 0; u < 4; ++u)
        if (k0 + c4 + u < K) { ta[u] = Arow[k0 + c4 + u]; tw[u] = Wrow[k0 + c4 + u]; }
      av.x = ta[0]; av.y = ta[1]; av.z = ta[2]; av.w = ta[3];
      wv.x = tw[0]; wv.y = tw[1]; wv.z = tw[2]; wv.w = tw[3];
    }
    __syncthreads();
    As[c4 + 0][r] = av.x; As[c4 + 1][r] = av.y; As[c4 + 2][r] = av.z; As[c4 + 3][r] = av.w;
    Ws[c4 + 0][r] = wv.x; Ws[c4 + 1][r] = wv.y; Ws[c4 + 2][r] = wv.z; Ws[c4 + 3][r] = wv.w;
    __syncthreads();
#pragma unroll
    for (int k = 0; k < 16; ++k) {
      const float4 a4 = *(const float4*)&As[k][ty << 2];
      const float4 b4 = *(const float4*)&Ws[k][tx << 2];
      acc[0][0] = fmaf(a4.x, b4.x, acc[0][0]);
      acc[0][1] = fmaf(a4.x, b4.y, acc[0][1]);
      acc[0][2] = fmaf(a4.x, b4.z, acc[0][2]);
      acc[0][3] = fmaf(a4.x, b4.w, acc[0][3]);
      acc[1][0] = fmaf(a4.y, b4.x, acc[1][0]);
      acc[1][1] = fmaf(a4.y, b4.y, acc[1][1]);
      acc[1][2] = fmaf(a4.y, b4.z, acc[1][2]);
      acc[1][3] = fmaf(a4.y, b4.w, acc[1][3]);
      acc[2][0] = fmaf(a4.z, b4.x, acc[2][0]);
      acc[2][1] = fmaf(a4.z, b4.y, acc[2][1]);
      acc[2][2] = fmaf(a4.z, b4.z, acc[2][2]);
      acc[2][3] = fmaf(a4.z, b4.w, acc[2][3]);
      acc[3][0] = fmaf(a4.w, b4.x, acc[3][0]);
      acc[3][1] = fmaf(a4.w, b4.y, acc[3][1]);
      acc[3][2] = fmaf(a4.w, b4.z, acc[3][2]);
      acc[3][3] = fmaf(a4.w, b4.w, acc[3][3]);
    }
  }
#pragma unroll
  for (int i = 0; i < 4; ++i) {
    const int m = bm * 64 + (ty << 2) + i;
#pragma unroll
    for (int j = 0; j < 4; ++j) {
      const int n = bn * 64 + (tx << 2) + j;
      float v = acc[i][j];
      if (BIAS) v += bias[n];
      if (TRANSP) C[(((long)(m >> 8) * N + n) << 8) + (m & 255)] = v;
      else        C[(long)m * N + n] = v;
    }
  }
}

// ============ sequential GRU, 256 threads, NO K-split, i8 resident ==========
// Thread j owns FULL K=256 for rows {j, H+j, 2H+j}: 48 uint4 = 192 i8-dwords
// pinned in VGPRs. r1 proved the compiler allocates >200 VGPR at 256-thread
// blocks; liveness here ~222 <= ~240 budget -> no stream, no spill. h kept as
// i8 in double-buffered LDS (uniform broadcast reads), 1 barrier/step, no
// cross-thread reduction (each thread computes its 3 gate rows completely).

__device__ __forceinline__ uint4 ld4q(const uint32_t* __restrict__ b, int row, int u) {
  uint4 v;
  v.x = b[(4 * u + 0) * G3 + row];
  v.y = b[(4 * u + 1) * G3 + row];
  v.z = b[(4 * u + 2) * G3 + row];
  v.w = b[(4 * u + 3) * G3 + row];
  return v;
}

#define PIN4(v) asm volatile("" : "+v"(v.x), "+v"(v.y), "+v"(v.z), "+v"(v.w))
#define WDECL16(p) uint4 p##0, p##1, p##2, p##3, p##4, p##5, p##6, p##7, \
                         p##8, p##9, p##10, p##11, p##12, p##13, p##14, p##15
#define WLOAD16(p, base, row) \
  p##0  = ld4q(base, row, 0);  p##1  = ld4q(base, row, 1);  \
  p##2  = ld4q(base, row, 2);  p##3  = ld4q(base, row, 3);  \
  p##4  = ld4q(base, row, 4);  p##5  = ld4q(base, row, 5);  \
  p##6  = ld4q(base, row, 6);  p##7  = ld4q(base, row, 7);  \
  p##8  = ld4q(base, row, 8);  p##9  = ld4q(base, row, 9);  \
  p##10 = ld4q(base, row, 10); p##11 = ld4q(base, row, 11); \
  p##12 = ld4q(base, row, 12); p##13 = ld4q(base, row, 13); \
  p##14 = ld4q(base, row, 14); p##15 = ld4q(base, row, 15)
#define WPIN16(p) \
  PIN4(p##0);  PIN4(p##1);  PIN4(p##2);  PIN4(p##3);  \
  PIN4(p##4);  PIN4(p##5);  PIN4(p##6);  PIN4(p##7);  \
  PIN4(p##8);  PIN4(p##9);  PIN4(p##10); PIN4(p##11); \
  PIN4(p##12); PIN4(p##13); PIN4(p##14); PIN4(p##15)

#define DOTC(c) { \
  const uint4 hp = hq[c]; \
  ar = sdot4(wr##c.x, hp.x, ar); az = sdot4(wz##c.x, hp.x, az); an = sdot4(wn##c.x, hp.x, an); \
  ar = sdot4(wr##c.y, hp.y, ar); az = sdot4(wz##c.y, hp.y, az); an = sdot4(wn##c.y, hp.y, an); \
  ar = sdot4(wr##c.z, hp.z, ar); az = sdot4(wz##c.z, hp.z, az); an = sdot4(wn##c.z, hp.z, an); \
  ar = sdot4(wr##c.w, hp.w, ar); az = sdot4(wz##c.w, hp.w, az); an = sdot4(wn##c.w, hp.w, an); }

__global__ __attribute__((amdgpu_flat_work_group_size(256, 256), amdgpu_waves_per_eu(1, 1)))
void gru_seq(const float* __restrict__ xg, const uint32_t* __restrict__ wQ,
             const float* __restrict__ sw, const float* __restrict__ bhh,
             const float* __restrict__ h0, float* __restrict__ hout,
             float* __restrict__ hlast, int S) {
  const int b = blockIdx.x;
  const int j = threadIdx.x;
  WDECL16(wr); WDECL16(wz); WDECL16(wn);
  WLOAD16(wr, wQ, j);
  WLOAD16(wz, wQ, H_ + j);
  WLOAD16(wn, wQ, 2 * H_ + j);
  WPIN16(wr); WPIN16(wz); WPIN16(wn);
  __shared__ __align__(16) uint32_t h2[2][H_ / 4];   // i8 h, double-buffered
  const float bhn = bhh[2 * H_ + j];
  const float swr = sw[j], swz = sw[H_ + j], swn = sw[2 * H_ + j];
  float h = h0 ? h0[b * H_ + j] : 0.0f;
  ((signed char*)h2[0])[j] = (signed char)__float2int_rn(h * 127.0f);
  const float* xp = xg + (long)b * S * G3;
  float* hp_out = hout + (long)b * S * H_;
  float xr = xp[j], xz = xp[H_ + j], xn = xp[2 * H_ + j];
  __syncthreads();
  for (int t = 0; t < S; ++t) {
    // prefetch next step's x under the dot chain
    float nxr = 0.0f, nxz = 0.0f, nxn = 0.0f;
    if (t + 1 < S) { nxr = xp[G3 + j]; nxz = xp[G3 + H_ + j]; nxn = xp[G3 + 2 * H_ + j]; }
    int ar = 0, az = 0, an = 0;
    const uint4* hq = (const uint4*)h2[t & 1];
    DOTC(0)  DOTC(1)
    __builtin_amdgcn_sched_barrier(0);
    DOTC(2)  DOTC(3)
    __builtin_amdgcn_sched_barrier(0);
    DOTC(4)  DOTC(5)
    __builtin_amdgcn_sched_barrier(0);
    DOTC(6)  DOTC(7)
    __builtin_amdgcn_sched_barrier(0);
    DOTC(8)  DOTC(9)
    __builtin_amdgcn_sched_barrier(0);
    DOTC(10) DOTC(11)
    __builtin_amdgcn_sched_barrier(0);
    DOTC(12) DOTC(13)
    __builtin_amdgcn_sched_barrier(0);
    DOTC(14) DOTC(15)
    const float r = sigmoid_f(xr + (float)ar * swr);       // xr has bih_r+bhh_r
    const float z = sigmoid_f(xz + (float)az * swz);       // xz has bih_z+bhh_z
    const float n = tanh_f(xn + r * ((float)an * swn + bhn));
    h = (1.0f - z) * n + z * h;
    hp_out[j] = h;
    ((signed char*)h2[(t & 1) ^ 1])[j] = (signed char)__float2int_rn(h * 127.0f);
    xr = nxr; xz = nxz; xn = nxn;
    xp += G3;
    hp_out += H_;
    __syncthreads();
  }
  if (hlast) hlast[b * H_ + j] = h;
}

// ---- fused pointer layer + masked log-softmax + loss accumulation ----
__global__ __launch_bounds__(256)
void pointer_loss(const float* __restrict__ WEt, const float* __restrict__ WD,
                  const float* __restrict__ Vv,
                  const int* __restrict__ Xindex, const int* __restrict__ Yindex,
                  const int* __restrict__ lens, float* __restrict__ out) {
  const int t = blockIdx.x, b = blockIdx.y;
  const int l = threadIdx.x;
  __shared__ float wd_s[H_], vv_s[H_];
  __shared__ float rbuf[4], sbuf[4], vy_s;
  const int bt = b * T_ + t;
  wd_s[l] = WD[(long)bt * H_ + l];
  vv_s[l] = Vv[l] * 1.0507009873554805f;
  __syncthreads();
  const float* wet = WEt + (long)b * H_ * L_;
  const float alpha = 1.6732632423543772f;
  float acc = 0.0f;
#pragma unroll 4
  for (int hh = 0; hh < H_; ++hh) {
    const float xsum = wet[hh * L_ + l] + wd_s[hh];
    const float sneg = alpha * (__expf(xsum) - 1.0f);
    const float s = xsum > 0.0f ? xsum : sneg;
    acc = fmaf(s, vv_s[hh], acc);
  }
  float v;
  {
    const float sneg = alpha * (__expf(acc) - 1.0f);
    v = 1.0507009873554805f * (acc > 0.0f ? acc : sneg);
  }
  const int start = Xindex[bt];
  const int len = lens[b];
  const bool valid = (l >= start) && (l < len);
  const int y = Yindex[bt];
  if (l == y) vy_s = v;
  float m = valid ? v : -INFINITY;
  for (int off = 32; off > 0; off >>= 1) m = fmaxf(m, __shfl_xor(m, off, 64));
  const int wid = l >> 6, lane = l & 63;
  if (lane == 0) rbuf[wid] = m;
  __syncthreads();
  const float mx = fmaxf(fmaxf(rbuf[0], rbuf[1]), fmaxf(rbuf[2], rbuf[3]));
  float e = valid ? __expf(v - mx) : 0.0f;
  for (int off = 32; off > 0; off >>= 1) e += __shfl_xor(e, off, 64);
  if (lane == 0) sbuf[wid] = e;
  __syncthreads();
  if (l == 0) {
    const float sum = sbuf[0] + sbuf[1] + sbuf[2] + sbuf[3];
    atomicAdd(out, (mx + __logf(sum) - vy_s) * (1.0f / (B_ * T_)));
  }
}

extern "C" void kernel_launch(void* const* d_in, const int* in_sizes, int n_in,
                              void* d_out, int out_size, void* d_ws, size_t ws_size,
                              hipStream_t stream) {
  (void)in_sizes; (void)n_in; (void)out_size; (void)ws_size;
  const int*   Xin    = (const int*)d_in[0];
  const int*   Xindex = (const int*)d_in[1];
  const int*   Yindex = (const int*)d_in[2];
  const int*   lens   = (const int*)d_in[3];
  const float* emb    = (const float*)d_in[4];
  const float* Wih_e  = (const float*)d_in[5];
  const float* Whh_e  = (const float*)d_in[6];
  const float* bih_e  = (const float*)d_in[7];
  const float* bhh_e  = (const float*)d_in[8];
  const float* Wih_d  = (const float*)d_in[9];
  const float* Whh_d  = (const float*)d_in[10];
  const float* bih_d  = (const float*)d_in[11];
  const float* bhh_d  = (const float*)d_in[12];
  const float* W1     = (const float*)d_in[13];
  const float* W2     = (const float*)d_in[14];
  const float* Vv     = (const float*)d_in[15];

  char* p = (char*)d_ws;
  auto take = [&](size_t bytes) { void* q = (void*)p; p += (bytes + 255) & ~(size_t)255; return q; };
  uint32_t* wQ_e = (uint32_t*)take((size_t)64 * G3 * 4);
  uint32_t* wQ_d = (uint32_t*)take((size_t)64 * G3 * 4);
  float* sw_e  = (float*)take((size_t)768 * 4);
  float* sw_d  = (float*)take((size_t)768 * 4);
  float* xg_e  = (float*)take((size_t)8192 * 768 * 4);
  float* xg_d  = (float*)take((size_t)1024 * 768 * 4);
  float* hn    = (float*)take((size_t)8192 * 256 * 4);
  float* hend  = (float*)take((size_t)8192 * 4);
  float* hl_d  = (float*)take((size_t)8192 * 4);
  float* doutb = (float*)take((size_t)1024 * 256 * 4);
  float* WEt   = (float*)take((size_t)8192 * 256 * 4);
  float* WDb   = (float*)take((size_t)1024 * 256 * 4);
  int*   dtok  = (int*)take((size_t)1024 * 4);
  float* bsum_e = (float*)take((size_t)768 * 4);
  float* bsum_d = (float*)take((size_t)768 * 4);

  hipMemsetAsync(d_out, 0, sizeof(float), stream);

  hipLaunchKernelGGL(pack_whh_i8, dim3(192), dim3(256), 0, stream, Whh_e, wQ_e, sw_e);
  hipLaunchKernelGGL(pack_whh_i8, dim3(192), dim3(256), 0, stream, Whh_d, wQ_d, sw_d);
  hipLaunchKernelGGL(bias_combine, dim3(3), dim3(256), 0, stream, bih_e, bhh_e, bsum_e);
  hipLaunchKernelGGL(bias_combine, dim3(3), dim3(256), 0, stream, bih_d, bhh_d, bsum_d);
  hipLaunchKernelGGL(gather_dtok, dim3(4), dim3(256), 0, stream, Xin, Xindex, dtok);

  // xg_e = emb[Xin] @ Wih_e^T + (bih_e + bhh_e|rz)   [8192 x 768], K=300
  hipLaunchKernelGGL((gemm_awt<true, false, true>), dim3(128, 12), dim3(256), 0, stream,
                     emb, Xin, Wih_e, bsum_e, xg_e, 8192, 768, 300);
  // xg_d = emb[dtok] @ Wih_d^T + (bih_d + bhh_d|rz)  [1024 x 768], K=300
  hipLaunchKernelGGL((gemm_awt<true, false, true>), dim3(16, 12), dim3(256), 0, stream,
                     emb, dtok, Wih_d, bsum_d, xg_d, 1024, 768, 300);

  // encoder GRU (h0 = 0), outputs hn [B,L,H] and hend [B,H]
  hipLaunchKernelGGL(gru_seq, dim3(32), dim3(256), 0, stream,
                     xg_e, wQ_e, sw_e, bhh_e, (const float*)nullptr, hn, hend, L_);
  // decoder GRU (h0 = hend), outputs doutb [B,T,H]
  hipLaunchKernelGGL(gru_seq, dim3(32), dim3(256), 0, stream,
                     xg_d, wQ_d, sw_d, bhh_d, hend, doutb, hl_d, T_);

  // WEt[b][k][l] = sum_h hn[b,l,h] * W1[k,h]   (transposed store)
  hipLaunchKernelGGL((gemm_awt<false, true, false>), dim3(128, 4), dim3(256), 0, stream,
                     hn, (const int*)nullptr, W1, (const float*)nullptr, WEt, 8192, 256, 256);
  // WD[b,t,k] = sum_h doutb[b,t,h] * W2[k,h]
  hipLaunchKernelGGL((gemm_awt<false, false, false>), dim3(16, 4), dim3(256), 0, stream,
                     doutb, (const int*)nullptr, W2, (const float*)nullptr, WDb, 1024, 256, 256);

  // fused pointer layer + loss
  hipLaunchKernelGGL(pointer_loss, dim3(T_, B_), dim3(256), 0, stream,
                     WEt, WDb, Vv, Xindex, Yindex, lens, (float*)d_out);
}

// Round 10
// 389.927 us; speedup vs baseline: 1.0418x; 1.0418x over previous
//
#include <hip/hip_runtime.h>
#include <hip/hip_bf16.h>
#include <stdint.h>

#define B_  32
#define L_  256
#define T_  32
#define D_  300
#define H_  256
#define G3  768   // 3*H

__device__ __forceinline__ int sdot4(uint32_t a, uint32_t b, int acc) {
#if defined(__has_builtin) && __has_builtin(__builtin_amdgcn_sdot4)
  return __builtin_amdgcn_sdot4((int)a, (int)b, acc, false);
#else
  const int a0 = (int)(signed char)(a & 0xff),  b0 = (int)(signed char)(b & 0xff);
  const int a1 = (int)(signed char)((a >> 8) & 0xff),  b1 = (int)(signed char)((b >> 8) & 0xff);
  const int a2 = (int)(signed char)((a >> 16) & 0xff), b2 = (int)(signed char)((b >> 16) & 0xff);
  const int a3 = (int)(signed char)(a >> 24),          b3 = (int)(signed char)(b >> 24);
  return acc + a0 * b0 + a1 * b1 + a2 * b2 + a3 * b3;
#endif
}

__device__ __forceinline__ float rcp_f(float x) { return __builtin_amdgcn_rcpf(x); }
__device__ __forceinline__ float sigmoid_f(float x) { return rcp_f(1.0f + __expf(-x)); }
__device__ __forceinline__ float tanh_f(float x) {
  float e2 = __expf(2.0f * x);
  return 1.0f - 2.0f * rcp_f(e2 + 1.0f);
}

// ---- pack Whh [768][256] f32 -> wQ i8 [64 kgroups][768 rows] + sw[768] ----
__global__ __launch_bounds__(256)
void pack_whh_i8(const float* __restrict__ Whh, uint32_t* __restrict__ wQ,
                 float* __restrict__ sw) {
  const int row = blockIdx.x * 4 + (threadIdx.x >> 6);
  const int lane = threadIdx.x & 63;
  const float* wr = Whh + (long)row * H_;
  float m = 0.0f;
#pragma unroll
  for (int u = 0; u < 4; ++u) m = fmaxf(m, fabsf(wr[lane + 64 * u]));
  for (int off = 32; off > 0; off >>= 1) m = fmaxf(m, __shfl_xor(m, off, 64));
  const float inv = m > 0.0f ? 127.0f / m : 0.0f;
  if (lane == 0) sw[row] = m > 0.0f ? m / (127.0f * 127.0f) : 0.0f;
  uint32_t d = 0;
#pragma unroll
  for (int u = 0; u < 4; ++u) {
    int qv = __float2int_rn(wr[4 * lane + u] * inv);
    qv = qv > 127 ? 127 : (qv < -127 ? -127 : qv);
    d |= ((uint32_t)(qv & 0xff)) << (8 * u);
  }
  wQ[lane * G3 + row] = d;
}

// ---- bsum = bih + bhh for gates r,z; bih only for gate n ----
__global__ void bias_combine(const float* __restrict__ bih, const float* __restrict__ bhh,
                             float* __restrict__ bsum) {
  const int i = blockIdx.x * 256 + threadIdx.x;   // 0..767
  float v = bih[i];
  if (i < 2 * H_) v += bhh[i];
  bsum[i] = v;
}

// ---- dtok[i] = Xin[b*L + Xindex[i]] ----
__global__ void gather_dtok(const int* __restrict__ Xin, const int* __restrict__ Xindex,
                            int* __restrict__ dtok) {
  const int i = blockIdx.x * 256 + threadIdx.x;   // 0..1023
  const int b = i >> 5;                           // /T_
  dtok[i] = Xin[b * L_ + Xindex[i]];
}

// ---- generic C = A @ W^T (+bias) ----
template<bool GATHER, bool TRANSP, bool BIAS>
__global__ __launch_bounds__(256)
void gemm_awt(const float* __restrict__ A, const int* __restrict__ rowidx,
              const float* __restrict__ W, const float* __restrict__ bias,
              float* __restrict__ C, int M, int N, int K) {
  __shared__ float As[16][68];
  __shared__ float Ws[16][68];
  const int tid = threadIdx.x;
  const int bm = blockIdx.x, bn = blockIdx.y;
  const int ty = tid >> 4, tx = tid & 15;
  const int r  = tid >> 2;
  const int c4 = (tid & 3) << 2;
  const long arow = (long)bm * 64 + r;
  const float* Arow = GATHER ? (A + (long)rowidx[arow] * K) : (A + arow * (long)K);
  const float* Wrow = W + ((long)bn * 64 + r) * K;
  float acc[4][4] = {};
  for (int k0 = 0; k0 < K; k0 += 16) {
    float4 av, wv;
    if (k0 + c4 + 3 < K) {
      av = *(const float4*)(Arow + k0 + c4);
      wv = *(const float4*)(Wrow + k0 + c4);
    } else {
      float ta[4] = {0, 0, 0, 0}, tw[4] = {0, 0, 0, 0};
      for (int u = 0; u < 4; ++u)
        if (k0 + c4 + u < K) { ta[u] = Arow[k0 + c4 + u]; tw[u] = Wrow[k0 + c4 + u]; }
      av.x = ta[0]; av.y = ta[1]; av.z = ta[2]; av.w = ta[3];
      wv.x = tw[0]; wv.y = tw[1]; wv.z = tw[2]; wv.w = tw[3];
    }
    __syncthreads();
    As[c4 + 0][r] = av.x; As[c4 + 1][r] = av.y; As[c4 + 2][r] = av.z; As[c4 + 3][r] = av.w;
    Ws[c4 + 0][r] = wv.x; Ws[c4 + 1][r] = wv.y; Ws[c4 + 2][r] = wv.z; Ws[c4 + 3][r] = wv.w;
    __syncthreads();
#pragma unroll
    for (int k = 0; k < 16; ++k) {
      const float4 a4 = *(const float4*)&As[k][ty << 2];
      const float4 b4 = *(const float4*)&Ws[k][tx << 2];
      acc[0][0] = fmaf(a4.x, b4.x, acc[0][0]);
      acc[0][1] = fmaf(a4.x, b4.y, acc[0][1]);
      acc[0][2] = fmaf(a4.x, b4.z, acc[0][2]);
      acc[0][3] = fmaf(a4.x, b4.w, acc[0][3]);
      acc[1][0] = fmaf(a4.y, b4.x, acc[1][0]);
      acc[1][1] = fmaf(a4.y, b4.y, acc[1][1]);
      acc[1][2] = fmaf(a4.y, b4.z, acc[1][2]);
      acc[1][3] = fmaf(a4.y, b4.w, acc[1][3]);
      acc[2][0] = fmaf(a4.z, b4.x, acc[2][0]);
      acc[2][1] = fmaf(a4.z, b4.y, acc[2][1]);
      acc[2][2] = fmaf(a4.z, b4.z, acc[2][2]);
      acc[2][3] = fmaf(a4.z, b4.w, acc[2][3]);
      acc[3][0] = fmaf(a4.w, b4.x, acc[3][0]);
      acc[3][1] = fmaf(a4.w, b4.y, acc[3][1]);
      acc[3][2] = fmaf(a4.w, b4.z, acc[3][2]);
      acc[3][3] = fmaf(a4.w, b4.w, acc[3][3]);
    }
  }
#pragma unroll
  for (int i = 0; i < 4; ++i) {
    const int m = bm * 64 + (ty << 2) + i;
#pragma unroll
    for (int j = 0; j < 4; ++j) {
      const int n = bn * 64 + (tx << 2) + j;
      float v = acc[i][j];
      if (BIAS) v += bias[n];
      if (TRANSP) C[(((long)(m >> 8) * N + n) << 8) + (m & 255)] = v;
      else        C[(long)m * N + n] = v;
    }
  }
}

// ============ sequential GRU, 768 threads, GATE-split, i8 resident ==========
// tid = g*256+j: thread owns row tid (gate g, unit j) with FULL K=256 as 16
// pinned uint4 (64 i8-dwords). No K-reduction. Liveness ~85 regs -- under
// every allocator grant observed (256thr:132-204, 512thr:128). Gate coupling
// via 2 small f32 LDS arrays: g0 publishes r, g1 publishes z, g2 computes
// n, updates h, republishes i8 h (double-buffered). 2 barriers/step.

__device__ __forceinline__ uint4 ld4q(const uint32_t* __restrict__ b, int row, int u) {
  uint4 v;
  v.x = b[(4 * u + 0) * G3 + row];
  v.y = b[(4 * u + 1) * G3 + row];
  v.z = b[(4 * u + 2) * G3 + row];
  v.w = b[(4 * u + 3) * G3 + row];
  return v;
}

#define PIN4(v) asm volatile("" : "+v"(v.x), "+v"(v.y), "+v"(v.z), "+v"(v.w))
#define WDECL16(p) uint4 p##0, p##1, p##2, p##3, p##4, p##5, p##6, p##7, \
                         p##8, p##9, p##10, p##11, p##12, p##13, p##14, p##15
#define WLOAD16(p, base, row) \
  p##0  = ld4q(base, row, 0);  p##1  = ld4q(base, row, 1);  \
  p##2  = ld4q(base, row, 2);  p##3  = ld4q(base, row, 3);  \
  p##4  = ld4q(base, row, 4);  p##5  = ld4q(base, row, 5);  \
  p##6  = ld4q(base, row, 6);  p##7  = ld4q(base, row, 7);  \
  p##8  = ld4q(base, row, 8);  p##9  = ld4q(base, row, 9);  \
  p##10 = ld4q(base, row, 10); p##11 = ld4q(base, row, 11); \
  p##12 = ld4q(base, row, 12); p##13 = ld4q(base, row, 13); \
  p##14 = ld4q(base, row, 14); p##15 = ld4q(base, row, 15)
#define WPIN16(p) \
  PIN4(p##0);  PIN4(p##1);  PIN4(p##2);  PIN4(p##3);  \
  PIN4(p##4);  PIN4(p##5);  PIN4(p##6);  PIN4(p##7);  \
  PIN4(p##8);  PIN4(p##9);  PIN4(p##10); PIN4(p##11); \
  PIN4(p##12); PIN4(p##13); PIN4(p##14); PIN4(p##15)

#define DOTG(c) { \
  const uint4 hp = hq[c]; \
  a = sdot4(w##c.x, hp.x, a); a = sdot4(w##c.y, hp.y, a); \
  a = sdot4(w##c.z, hp.z, a); a = sdot4(w##c.w, hp.w, a); }

__global__ __attribute__((amdgpu_flat_work_group_size(768, 768), amdgpu_waves_per_eu(3, 3)))
void gru_seq(const float* __restrict__ xg, const uint32_t* __restrict__ wQ,
             const float* __restrict__ sw, const float* __restrict__ bhh,
             const float* __restrict__ h0, float* __restrict__ hout,
             float* __restrict__ hlast, int S) {
  const int b = blockIdx.x;
  const int tid = threadIdx.x;     // row = g*256 + j
  const int j = tid & 255;
  const int g = tid >> 8;
  WDECL16(w);
  WLOAD16(w, wQ, tid);
  WPIN16(w);
  __shared__ __align__(16) uint32_t h2[2][H_ / 4];   // i8 h, double-buffered
  __shared__ float r_lds[H_], z_lds[H_];
  const float swg = sw[tid];
  float bhn = 0.0f, h = 0.0f;
  if (g == 2) {
    bhn = bhh[2 * H_ + j];
    h = h0 ? h0[b * H_ + j] : 0.0f;
    ((signed char*)h2[0])[j] = (signed char)__float2int_rn(h * 127.0f);
  }
  const float* xp = xg + (long)b * S * G3;
  float* hp_out = hout + (long)b * S * H_;
  float xv = xp[tid];              // own gate's x only (bih+bhh folded for r,z)
  __syncthreads();
  for (int t = 0; t < S; ++t) {
    int a = 0;
    const uint4* hq = (const uint4*)h2[t & 1];
    DOTG(0)  DOTG(1)  DOTG(2)  DOTG(3)
    __builtin_amdgcn_sched_barrier(0);
    DOTG(4)  DOTG(5)  DOTG(6)  DOTG(7)
    __builtin_amdgcn_sched_barrier(0);
    DOTG(8)  DOTG(9)  DOTG(10) DOTG(11)
    __builtin_amdgcn_sched_barrier(0);
    DOTG(12) DOTG(13) DOTG(14) DOTG(15)
    const float af = (float)a * swg;
    float nxv = 0.0f;
    if (t + 1 < S) nxv = xp[G3 + tid];   // prefetch next x
    if (g == 0)      r_lds[j] = sigmoid_f(xv + af);
    else if (g == 1) z_lds[j] = sigmoid_f(xv + af);
    __syncthreads();
    if (g == 2) {
      const float r = r_lds[j], z = z_lds[j];
      const float n = tanh_f(xv + r * (af + bhn));
      h = (1.0f - z) * n + z * h;
      hp_out[j] = h;
      ((signed char*)h2[(t & 1) ^ 1])[j] = (signed char)__float2int_rn(h * 127.0f);
    }
    xv = nxv;
    xp += G3;
    hp_out += H_;
    __syncthreads();
  }
  if (g == 2 && hlast) hlast[b * H_ + j] = h;
}

// ---- fused pointer layer + masked log-softmax + loss accumulation ----
__global__ __launch_bounds__(256)
void pointer_loss(const float* __restrict__ WEt, const float* __restrict__ WD,
                  const float* __restrict__ Vv,
                  const int* __restrict__ Xindex, const int* __restrict__ Yindex,
                  const int* __restrict__ lens, float* __restrict__ out) {
  const int t = blockIdx.x, b = blockIdx.y;
  const int l = threadIdx.x;
  __shared__ float wd_s[H_], vv_s[H_];
  __shared__ float rbuf[4], sbuf[4], vy_s;
  const int bt = b * T_ + t;
  wd_s[l] = WD[(long)bt * H_ + l];
  vv_s[l] = Vv[l] * 1.0507009873554805f;
  __syncthreads();
  const float* wet = WEt + (long)b * H_ * L_;
  const float alpha = 1.6732632423543772f;
  float acc = 0.0f;
#pragma unroll 4
  for (int hh = 0; hh < H_; ++hh) {
    const float xsum = wet[hh * L_ + l] + wd_s[hh];
    const float sneg = alpha * (__expf(xsum) - 1.0f);
    const float s = xsum > 0.0f ? xsum : sneg;
    acc = fmaf(s, vv_s[hh], acc);
  }
  float v;
  {
    const float sneg = alpha * (__expf(acc) - 1.0f);
    v = 1.0507009873554805f * (acc > 0.0f ? acc : sneg);
  }
  const int start = Xindex[bt];
  const int len = lens[b];
  const bool valid = (l >= start) && (l < len);
  const int y = Yindex[bt];
  if (l == y) vy_s = v;
  float m = valid ? v : -INFINITY;
  for (int off = 32; off > 0; off >>= 1) m = fmaxf(m, __shfl_xor(m, off, 64));
  const int wid = l >> 6, lane = l & 63;
  if (lane == 0) rbuf[wid] = m;
  __syncthreads();
  const float mx = fmaxf(fmaxf(rbuf[0], rbuf[1]), fmaxf(rbuf[2], rbuf[3]));
  float e = valid ? __expf(v - mx) : 0.0f;
  for (int off = 32; off > 0; off >>= 1) e += __shfl_xor(e, off, 64);
  if (lane == 0) sbuf[wid] = e;
  __syncthreads();
  if (l == 0) {
    const float sum = sbuf[0] + sbuf[1] + sbuf[2] + sbuf[3];
    atomicAdd(out, (mx + __logf(sum) - vy_s) * (1.0f / (B_ * T_)));
  }
}

extern "C" void kernel_launch(void* const* d_in, const int* in_sizes, int n_in,
                              void* d_out, int out_size, void* d_ws, size_t ws_size,
                              hipStream_t stream) {
  (void)in_sizes; (void)n_in; (void)out_size; (void)ws_size;
  const int*   Xin    = (const int*)d_in[0];
  const int*   Xindex = (const int*)d_in[1];
  const int*   Yindex = (const int*)d_in[2];
  const int*   lens   = (const int*)d_in[3];
  const float* emb    = (const float*)d_in[4];
  const float* Wih_e  = (const float*)d_in[5];
  const float* Whh_e  = (const float*)d_in[6];
  const float* bih_e  = (const float*)d_in[7];
  const float* bhh_e  = (const float*)d_in[8];
  const float* Wih_d  = (const float*)d_in[9];
  const float* Whh_d  = (const float*)d_in[10];
  const float* bih_d  = (const float*)d_in[11];
  const float* bhh_d  = (const float*)d_in[12];
  const float* W1     = (const float*)d_in[13];
  const float* W2     = (const float*)d_in[14];
  const float* Vv     = (const float*)d_in[15];

  char* p = (char*)d_ws;
  auto take = [&](size_t bytes) { void* q = (void*)p; p += (bytes + 255) & ~(size_t)255; return q; };
  uint32_t* wQ_e = (uint32_t*)take((size_t)64 * G3 * 4);
  uint32_t* wQ_d = (uint32_t*)take((size_t)64 * G3 * 4);
  float* sw_e  = (float*)take((size_t)768 * 4);
  float* sw_d  = (float*)take((size_t)768 * 4);
  float* xg_e  = (float*)take((size_t)8192 * 768 * 4);
  float* xg_d  = (float*)take((size_t)1024 * 768 * 4);
  float* hn    = (float*)take((size_t)8192 * 256 * 4);
  float* hend  = (float*)take((size_t)8192 * 4);
  float* hl_d  = (float*)take((size_t)8192 * 4);
  float* doutb = (float*)take((size_t)1024 * 256 * 4);
  float* WEt   = (float*)take((size_t)8192 * 256 * 4);
  float* WDb   = (float*)take((size_t)1024 * 256 * 4);
  int*   dtok  = (int*)take((size_t)1024 * 4);
  float* bsum_e = (float*)take((size_t)768 * 4);
  float* bsum_d = (float*)take((size_t)768 * 4);

  hipMemsetAsync(d_out, 0, sizeof(float), stream);

  hipLaunchKernelGGL(pack_whh_i8, dim3(192), dim3(256), 0, stream, Whh_e, wQ_e, sw_e);
  hipLaunchKernelGGL(pack_whh_i8, dim3(192), dim3(256), 0, stream, Whh_d, wQ_d, sw_d);
  hipLaunchKernelGGL(bias_combine, dim3(3), dim3(256), 0, stream, bih_e, bhh_e, bsum_e);
  hipLaunchKernelGGL(bias_combine, dim3(3), dim3(256), 0, stream, bih_d, bhh_d, bsum_d);
  hipLaunchKernelGGL(gather_dtok, dim3(4), dim3(256), 0, stream, Xin, Xindex, dtok);

  // xg_e = emb[Xin] @ Wih_e^T + (bih_e + bhh_e|rz)   [8192 x 768], K=300
  hipLaunchKernelGGL((gemm_awt<true, false, true>), dim3(128, 12), dim3(256), 0, stream,
                     emb, Xin, Wih_e, bsum_e, xg_e, 8192, 768, 300);
  // xg_d = emb[dtok] @ Wih_d^T + (bih_d + bhh_d|rz)  [1024 x 768], K=300
  hipLaunchKernelGGL((gemm_awt<true, false, true>), dim3(16, 12), dim3(256), 0, stream,
                     emb, dtok, Wih_d, bsum_d, xg_d, 1024, 768, 300);

  // encoder GRU (h0 = 0), outputs hn [B,L,H] and hend [B,H]
  hipLaunchKernelGGL(gru_seq, dim3(32), dim3(768), 0, stream,
                     xg_e, wQ_e, sw_e, bhh_e, (const float*)nullptr, hn, hend, L_);
  // decoder GRU (h0 = hend), outputs doutb [B,T,H]
  hipLaunchKernelGGL(gru_seq, dim3(32), dim3(768), 0, stream,
                     xg_d, wQ_d, sw_d, bhh_d, hend, doutb, hl_d, T_);

  // WEt[b][k][l] = sum_h hn[b,l,h] * W1[k,h]   (transposed store)
  hipLaunchKernelGGL((gemm_awt<false, true, false>), dim3(128, 4), dim3(256), 0, stream,
                     hn, (const int*)nullptr, W1, (const float*)nullptr, WEt, 8192, 256, 256);
  // WD[b,t,k] = sum_h doutb[b,t,h] * W2[k,h]
  hipLaunchKernelGGL((gemm_awt<false, false, false>), dim3(16, 4), dim3(256), 0, stream,
                     doutb, (const int*)nullptr, W2, (const float*)nullptr, WDb, 1024, 256, 256);

  // fused pointer layer + loss
  hipLaunchKernelGGL(pointer_loss, dim3(T_, B_), dim3(256), 0, stream,
                     WEt, WDb, Vv, Xindex, Yindex, lens, (float*)d_out);
}